// Round 8
// baseline (1963.144 us; speedup 1.0000x reference)
//
#include <hip/hip_runtime.h>

// OnlineLSTM: B=8192, T=2048, I=1, H=50.
// BARRIER-FREE recurrence (R7 structure, spill fixed): one wave owns 4 batch
// rows AND all 50 hidden columns -> h never crosses waves, zero __syncthreads
// in the t-loop. R7 failed because the compiler spilled the bfrag[4][4][2]
// ARRAY to scratch (WRITE_SIZE 65 MB, VGPR_Count 88): MFMA operands came from
// buffer_loads each step. Fix: 32 individually-NAMED half8 fragments via
// token pasting — no arrays, no loops — so they must live in registers.
// Batch rows at MFMA A-rows m=4b: C rows quad*4+r valid exactly at r=0 ->
// gate math = 4 full-wave gate_pair slots (28 transc/wave-step).
// K padded 50->64; k=50 carries x_t, k=51 carries 1.0 so MFMA output IS the
// exp2 argument (weights prescaled by -log2e for i,f,o / +2log2e for g).
// Grid: 8192/4 rows = 2048 waves = 512 blocks = 2 blocks/CU = 2 waves/SIMD.

#define HID   50
#define NSTEP 2048
#define HSTR  72     // fp16 elems per h row (144 B, 16B-aligned for b128)

typedef _Float16 half8   __attribute__((ext_vector_type(8)));
typedef float    float4v __attribute__((ext_vector_type(4)));

__device__ __forceinline__ float gate_pair(float zi, float zf, float zg, float zo,
                                           float& c) {
    // zi,zf,zo = -log2e * raw;  zg = 2log2e * raw  (prescaled in weights)
    float ei = __builtin_amdgcn_exp2f(zi);   // e^{-i_raw}
    float ef = __builtin_amdgcn_exp2f(zf);
    float Eg = __builtin_amdgcn_exp2f(zg);   // e^{2 g_raw}
    float eo = __builtin_amdgcn_exp2f(zo);
    float t1  = (1.0f + ei) * (1.0f + Eg);
    float num = c * t1 + (1.0f + ef) * (Eg - 1.0f);
    float D   = t1 * (1.0f + ef);
    c = num * __builtin_amdgcn_rcpf(D);
    float a  = fminf(fmaxf(2.8853900817779268f * c, -24.0f), 24.0f);
    float Ec = __builtin_amdgcn_exp2f(a);    // e^{2c}
    return (Ec - 1.0f) * __builtin_amdgcn_rcpf((1.0f + eo) * (1.0f + Ec));
}

// one B fragment: tile (gate g, j-tile jt), k-half kt; lane = (quad, col)
__device__ __forceinline__ half8 frag_load(int g, int jt, int kt, int col, int quad,
                                           const float* __restrict__ W_hh,
                                           const float* __restrict__ W_ih,
                                           const float* __restrict__ b_ih,
                                           const float* __restrict__ b_hh) {
    const float LOG2E = 1.4426950408889634f;
    const float sc = (g == 2) ? (2.0f * LOG2E) : (-LOG2E);
    const int j = jt * 16 + col;
    half8 f;
    #pragma unroll
    for (int jj = 0; jj < 8; ++jj) {
        int k = kt * 32 + quad * 8 + jj;
        float v = 0.0f;
        if (j < HID) {
            int row = g * HID + j;
            if (k < HID)           v = W_hh[row * HID + k];
            else if (k == HID)     v = W_ih[row];
            else if (k == HID + 1) v = b_ih[row] + b_hh[row];
        }
        f[jj] = (_Float16)(v * sc);
    }
    return f;
}

__global__ __launch_bounds__(256, 2) void lstm_fused(
    const float* __restrict__ x,
    const float* __restrict__ W_ih,
    const float* __restrict__ W_hh,
    const float* __restrict__ b_ih,
    const float* __restrict__ b_hh,
    const float* __restrict__ W_lin,
    const float* __restrict__ b_lin,
    float* __restrict__ out)
{
    __shared__ __align__(16) _Float16 hbuf[4][16][HSTR];  // per-wave slice

    const int tid  = threadIdx.x;
    const int wave = tid >> 6;
    const int lane = tid & 63;
    const int col  = lane & 15;
    const int quad = lane >> 4;
    const int b0   = blockIdx.x * 16 + wave * 4;    // this wave's batch rows
    _Float16 (*hb)[HSTR] = hbuf[wave];
    const int hrow = 4 * quad;                      // LDS row for b = b0+quad

    // ---- init own slice: zeros; x_0 at [4b][50]; 1.0 at [4b][51] ----
    for (int i = lane; i < 16 * HSTR; i += 64)
        (&hb[0][0])[i] = (_Float16)0.0f;
    if (col == 0) {
        hb[hrow][HID]     = (_Float16)x[(size_t)(b0 + quad) * NSTEP];
        hb[hrow][HID + 1] = (_Float16)1.0f;
    }

    // ---- 32 persistent B fragments as NAMED registers (no array!) ----
#define FRAG(G, JT, KT) \
    half8 bf_##G##_##JT##_##KT = frag_load(G, JT, KT, col, quad, W_hh, W_ih, b_ih, b_hh);
#define FRAG_JT(JT) FRAG(0, JT, 0) FRAG(1, JT, 0) FRAG(2, JT, 0) FRAG(3, JT, 0) \
                    FRAG(0, JT, 1) FRAG(1, JT, 1) FRAG(2, JT, 1) FRAG(3, JT, 1)
    FRAG_JT(0) FRAG_JT(1) FRAG_JT(2) FRAG_JT(3)
#undef FRAG_JT
#undef FRAG

    float c0 = 0.f, c1 = 0.f, c2 = 0.f, c3 = 0.f;  // c for (b=quad, j=16*jt+col)
    const float* xrow = x + (size_t)(b0 + quad) * NSTEP;
    const float4v Z4 = {0.f, 0.f, 0.f, 0.f};

#define MFMA16(A, B, C) __builtin_amdgcn_mfma_f32_16x16x32_f16(A, B, C, 0, 0, 0)
#define DOJT(JT, CC)                                                             \
    {                                                                            \
        float4v d0 = MFMA16(a0, bf_0_##JT##_0, Z4);                              \
        float4v d1 = MFMA16(a0, bf_1_##JT##_0, Z4);                              \
        float4v d2 = MFMA16(a0, bf_2_##JT##_0, Z4);                              \
        float4v d3 = MFMA16(a0, bf_3_##JT##_0, Z4);                              \
        d0 = MFMA16(a1, bf_0_##JT##_1, d0);                                      \
        d1 = MFMA16(a1, bf_1_##JT##_1, d1);                                      \
        d2 = MFMA16(a1, bf_2_##JT##_1, d2);                                      \
        d3 = MFMA16(a1, bf_3_##JT##_1, d3);                                      \
        float h = gate_pair(d0[0], d1[0], d2[0], d3[0], CC);                     \
        const int j = JT * 16 + col;                                             \
        if (j < HID)                                                             \
            hb[hrow][j] = (_Float16)h;                                           \
    }

    for (int t = 0; t < NSTEP; ++t) {
        float xn = 0.f;
        if (col == 0) {
            int tt = (t + 1 < NSTEP) ? (t + 1) : (NSTEP - 1);
            xn = xrow[tt];
        }
        // A fragments: A[m=col][k=quad*8+jj (+32)] — single buffer; this
        // step's reads precede its writes in program order (in-order DS pipe).
        const _Float16* arow = &hb[col][0];
        half8 a0 = *(const half8*)(arow + quad * 8);
        half8 a1 = *(const half8*)(arow + 32 + quad * 8);

        DOJT(0, c0) DOJT(1, c1) DOJT(2, c2) DOJT(3, c3)

        if (col == 0)
            hb[hrow][HID] = (_Float16)xn;
    }
#undef DOJT
#undef MFMA16

    // ---- epilogue: out[b] = h_last . W_lin + b_lin ----
    if (col == 0) {
        float s = b_lin[0];
        for (int k = 0; k < HID; ++k)
            s += (float)hb[hrow][k] * W_lin[k];
        out[b0 + quad] = s;
    }
}

extern "C" void kernel_launch(void* const* d_in, const int* in_sizes, int n_in,
                              void* d_out, int out_size, void* d_ws, size_t ws_size,
                              hipStream_t stream) {
    const float* x     = (const float*)d_in[0];
    const float* W_ih  = (const float*)d_in[1];
    const float* W_hh  = (const float*)d_in[2];
    const float* b_ih  = (const float*)d_in[3];
    const float* b_hh  = (const float*)d_in[4];
    const float* W_lin = (const float*)d_in[5];
    const float* b_lin = (const float*)d_in[6];
    float* outp = (float*)d_out;
    dim3 grid(8192 / 16), block(256);   // 4 waves/block, 4 rows/wave
    hipLaunchKernelGGL(lstm_fused, grid, block, 0, stream,
                       x, W_ih, W_hh, b_ih, b_hh, W_lin, b_lin, outp);
}

// Round 9
// 1355.530 us; speedup vs baseline: 1.4482x; 1.4482x over previous
//
#include <hip/hip_runtime.h>

// OnlineLSTM: B=8192, T=2048, I=1, H=50.
// R4 structure (best so far: 1366 us) + ANTI-PHASE STAGGER: odd blocks sleep
// ~960 cyc once before the t-loop so the two barrier domains sharing each CU
// run half-a-step out of phase — one block's waves issue while the other's
// stall at their barrier. R4-R8 established: rows/CU fixed at 32, per-SIMD
// issue conserved ~1040 cyc/step; runtime 1655 = issue + 612 stall. This
// round attacks only the stall; all else is bit-identical to R4.
// Block = 16 batch rows, 4 waves (256 thr), grid 512 = 2 blocks/CU.
// Wave jt owns j-columns 16jt..16jt+15 for ALL 4 gates (gate-major N=256).
// K padded 50->64; k=50 carries x_t, k=51 carries 1.0 so MFMA output IS the
// exp2 argument (weights prescaled by -log2e for i,f,o / +2log2e for g).
// Gate algebra: common-denominator form, 7 transcendentals per (b,j).

#define HID   50
#define NSTEP 2048
#define BPB   16
#define HSTR  72     // fp16 elems per hbuf row

typedef _Float16 half8   __attribute__((ext_vector_type(8)));
typedef float    float4v __attribute__((ext_vector_type(4)));

__device__ __forceinline__ float gate_pair(float zi, float zf, float zg, float zo,
                                           float& c) {
    // zi,zf,zo = -log2e * raw;  zg = 2log2e * raw  (prescaled in weights)
    float ei = __builtin_amdgcn_exp2f(zi);   // e^{-i_raw}
    float ef = __builtin_amdgcn_exp2f(zf);
    float Eg = __builtin_amdgcn_exp2f(zg);   // e^{2 g_raw}
    float eo = __builtin_amdgcn_exp2f(zo);
    float t1  = (1.0f + ei) * (1.0f + Eg);
    float num = c * t1 + (1.0f + ef) * (Eg - 1.0f);
    float D   = t1 * (1.0f + ef);
    c = num * __builtin_amdgcn_rcpf(D);
    float a  = fminf(fmaxf(2.8853900817779268f * c, -24.0f), 24.0f);
    float Ec = __builtin_amdgcn_exp2f(a);    // e^{2c}
    return (Ec - 1.0f) * __builtin_amdgcn_rcpf((1.0f + eo) * (1.0f + Ec));
}

__global__ __launch_bounds__(256, 2) void lstm_fused(
    const float* __restrict__ x,
    const float* __restrict__ W_ih,
    const float* __restrict__ W_hh,
    const float* __restrict__ b_ih,
    const float* __restrict__ b_hh,
    const float* __restrict__ W_lin,
    const float* __restrict__ b_lin,
    float* __restrict__ out)
{
    __shared__ __align__(16) _Float16 hbuf[2][BPB][HSTR];

    const int tid  = threadIdx.x;
    const int wave = tid >> 6;
    const int lane = tid & 63;
    const int col  = lane & 15;
    const int quad = lane >> 4;
    const int b0   = blockIdx.x * BPB;
    const int j    = wave * 16 + col;

    // ---- init h buffers: zeros, x_0 at col 50, 1.0 at col 51 ----
    for (int i = tid; i < 2 * BPB * HSTR; i += 256)
        (&hbuf[0][0][0])[i] = (_Float16)0.0f;
    __syncthreads();
    if (tid < BPB) {
        hbuf[0][tid][HID]     = (_Float16)x[(size_t)(b0 + tid) * NSTEP];
        hbuf[0][tid][HID + 1] = (_Float16)1.0f;
        hbuf[1][tid][HID + 1] = (_Float16)1.0f;
    }

    // ---- persistent B fragments, prescaled per gate ----
    const float LOG2E = 1.4426950408889634f;
    half8 bfrag[4][2];
    for (int g = 0; g < 4; ++g) {
        const float sc = (g == 2) ? (2.0f * LOG2E) : (-LOG2E);
        for (int kt = 0; kt < 2; ++kt) {
            half8 f;
            #pragma unroll
            for (int jj = 0; jj < 8; ++jj) {
                int k = kt * 32 + quad * 8 + jj;
                float v = 0.0f;
                if (j < HID) {
                    int row = g * HID + j;
                    if (k < HID)           v = W_hh[row * HID + k];
                    else if (k == HID)     v = W_ih[row];
                    else if (k == HID + 1) v = b_ih[row] + b_hh[row];
                }
                f[jj] = (_Float16)(v * sc);
            }
            bfrag[g][kt] = f;
        }
    }

    float c[4] = {0.f, 0.f, 0.f, 0.f};
    const bool xloader = (wave == 3) && (quad == 0);
    const float* xrow = x + (size_t)(b0 + col) * NSTEP;
    const float4v Z4 = {0.f, 0.f, 0.f, 0.f};

    __syncthreads();

    // ---- anti-phase stagger: odd blocks start ~960 cyc (half a step) late,
    // so the two barrier domains on each CU alternate issue/stall ----
    if (blockIdx.x & 1) {
        __builtin_amdgcn_s_sleep(15);
    }

#define STEP(CUR, NXT, T)                                                        \
    {                                                                            \
        float xn = 0.f;                                                          \
        if (xloader) {                                                           \
            int tt = ((T) + 1 < NSTEP) ? ((T) + 1) : (NSTEP - 1);                \
            xn = xrow[tt];                                                       \
        }                                                                        \
        const _Float16* arow = &hbuf[CUR][col][0];                               \
        half8 a0 = *(const half8*)(arow + quad * 8);                             \
        half8 a1 = *(const half8*)(arow + 32 + quad * 8);                        \
        float4v d0, d1, d2, d3;                                                  \
        d0 = __builtin_amdgcn_mfma_f32_16x16x32_f16(a0, bfrag[0][0], Z4, 0, 0, 0); \
        d1 = __builtin_amdgcn_mfma_f32_16x16x32_f16(a0, bfrag[1][0], Z4, 0, 0, 0); \
        d2 = __builtin_amdgcn_mfma_f32_16x16x32_f16(a0, bfrag[2][0], Z4, 0, 0, 0); \
        d3 = __builtin_amdgcn_mfma_f32_16x16x32_f16(a0, bfrag[3][0], Z4, 0, 0, 0); \
        d0 = __builtin_amdgcn_mfma_f32_16x16x32_f16(a1, bfrag[0][1], d0, 0, 0, 0); \
        d1 = __builtin_amdgcn_mfma_f32_16x16x32_f16(a1, bfrag[1][1], d1, 0, 0, 0); \
        d2 = __builtin_amdgcn_mfma_f32_16x16x32_f16(a1, bfrag[2][1], d2, 0, 0, 0); \
        d3 = __builtin_amdgcn_mfma_f32_16x16x32_f16(a1, bfrag[3][1], d3, 0, 0, 0); \
        _Float16 hv[4];                                                          \
        _Pragma("unroll")                                                        \
        for (int r = 0; r < 4; ++r)                                              \
            hv[r] = (_Float16)gate_pair(d0[r], d1[r], d2[r], d3[r], c[r]);       \
        if (j < HID) {                                                           \
            _Pragma("unroll")                                                    \
            for (int r = 0; r < 4; ++r)                                          \
                hbuf[NXT][quad * 4 + r][j] = hv[r];                              \
        }                                                                        \
        if (xloader)                                                             \
            hbuf[NXT][col][HID] = (_Float16)xn;                                  \
        __syncthreads();                                                         \
    }

    for (int t = 0; t < NSTEP; t += 2) {
        STEP(0, 1, t)
        STEP(1, 0, t + 1)
    }
#undef STEP

    // ---- epilogue: out[b] = h_last . W_lin + b_lin ; final h is in hbuf[0] ----
    if (tid < BPB) {
        float s = b_lin[0];
        for (int k = 0; k < HID; ++k)
            s += (float)hbuf[0][tid][k] * W_lin[k];
        out[b0 + tid] = s;
    }
}

extern "C" void kernel_launch(void* const* d_in, const int* in_sizes, int n_in,
                              void* d_out, int out_size, void* d_ws, size_t ws_size,
                              hipStream_t stream) {
    const float* x     = (const float*)d_in[0];
    const float* W_ih  = (const float*)d_in[1];
    const float* W_hh  = (const float*)d_in[2];
    const float* b_ih  = (const float*)d_in[3];
    const float* b_hh  = (const float*)d_in[4];
    const float* W_lin = (const float*)d_in[5];
    const float* b_lin = (const float*)d_in[6];
    float* outp = (float*)d_out;
    dim3 grid(8192 / BPB), block(256);
    hipLaunchKernelGGL(lstm_fused, grid, block, 0, stream,
                       x, W_ih, W_hh, b_ih, b_hh, W_lin, b_lin, outp);
}